// Round 7
// baseline (184.936 us; speedup 1.0000x reference)
//
#include <hip/hip_runtime.h>
#include <hip/hip_fp16.h>

#define Bb 4
#define Ss 1024
#define HID 1024
#define NH 16
#define NKV 8
#define HD 64

typedef _Float16 f16x8 __attribute__((ext_vector_type(8)));
typedef _Float16 f16x4 __attribute__((ext_vector_type(4)));
typedef float f32x4 __attribute__((ext_vector_type(4)));

typedef const __attribute__((address_space(1))) unsigned int gu32;
typedef __attribute__((address_space(3))) unsigned int lu32;

__device__ __forceinline__ void gl_lds16(const _Float16* g, _Float16* l) {
  __builtin_amdgcn_global_load_lds((gu32*)g, (lu32*)l, 16, 0, 0);
}

// ------------- fused fp32 -> fp16 conversion (all 5 tensors, one launch) ----
__global__ __launch_bounds__(256) void f2h_all(
    const float* __restrict__ a0, const float* __restrict__ a1,
    const float* __restrict__ a2, const float* __restrict__ a3,
    const float* __restrict__ a4, _Float16* __restrict__ o0,
    _Float16* __restrict__ o1, _Float16* __restrict__ o2,
    _Float16* __restrict__ o3, _Float16* __restrict__ o4) {
  const int bid = blockIdx.x;
  const float* src;
  _Float16* dst;
  int base;
  if (bid < 4096)      { src = a0; dst = o0; base = bid; }
  else if (bid < 5120) { src = a1; dst = o1; base = bid - 4096; }
  else if (bid < 5632) { src = a2; dst = o2; base = bid - 5120; }
  else if (bid < 6144) { src = a3; dst = o3; base = bid - 5632; }
  else                 { src = a4; dst = o4; base = bid - 6144; }
  const int i = base * 1024 + threadIdx.x * 4;
  const float4 v = *(const float4*)(src + i);
  f16x4 h;
  h[0] = (_Float16)v.x; h[1] = (_Float16)v.y;
  h[2] = (_Float16)v.z; h[3] = (_Float16)v.w;
  *(f16x4*)(dst + i) = h;
}

// ------------- MFMA GEMM, BM=BN=128 BK=32 (m97 structure), QKV epilogue ----
// 4 waves in 2x2: wave (wr,wc) owns rows wr*64.., cols wc*64.. (64 cols = 1 head).
// EPI=1: head hd2 = by*2+wc; hd2<16 -> Q rmsrope, <24 -> K rmsrope, else V -> vT.
template <int EPI>
__global__ __launch_bounds__(256) void gemm128(
    const _Float16* __restrict__ A, const _Float16* __restrict__ Bt,
    float* __restrict__ C, _Float16* __restrict__ qh, _Float16* __restrict__ kh,
    _Float16* __restrict__ vTp, const float* __restrict__ qnw,
    const float* __restrict__ knw, const float* __restrict__ cosd,
    const float* __restrict__ sind, int N, int K) {
  __shared__ __align__(16) _Float16 As[128][32];
  __shared__ __align__(16) _Float16 Bs[128][32];
  const int tid = threadIdx.x;
  const int wave = tid >> 6, lane = tid & 63;
  const int lr = lane & 15, lk = lane >> 4;
  const int wr = wave >> 1, wc = wave & 1;
  const int bm = blockIdx.x * 128;
  const int by = blockIdx.y;
  const int bn = by * 128;

  f32x4 acc[4][4] = {};

  const int ca0 = wave * 128 + lane;  // 16B chunk ids; each thread: ca0, ca0+64
  const _Float16* Arow0 = A + (size_t)(bm + (ca0 >> 2)) * K + (ca0 & 3) * 8;
  const _Float16* Arow1 = A + (size_t)(bm + ((ca0 + 64) >> 2)) * K + ((ca0 + 64) & 3) * 8;
  const _Float16* Brow0 = Bt + (size_t)(bn + (ca0 >> 2)) * K + (ca0 & 3) * 8;
  const _Float16* Brow1 = Bt + (size_t)(bn + ((ca0 + 64) >> 2)) * K + ((ca0 + 64) & 3) * 8;
  _Float16* lA0 = &As[0][0] + ca0 * 8;
  _Float16* lA1 = &As[0][0] + (ca0 + 64) * 8;
  _Float16* lB0 = &Bs[0][0] + ca0 * 8;
  _Float16* lB1 = &Bs[0][0] + (ca0 + 64) * 8;

  for (int k0 = 0; k0 < K; k0 += 32) {
    __syncthreads();
    gl_lds16(Arow0 + k0, lA0);
    gl_lds16(Arow1 + k0, lA1);
    gl_lds16(Brow0 + k0, lB0);
    gl_lds16(Brow1 + k0, lB1);
    __syncthreads();
    f16x8 af[4], bf[4];
#pragma unroll
    for (int m = 0; m < 4; ++m)
      af[m] = *(const f16x8*)&As[wr * 64 + m * 16 + lr][lk * 8];
#pragma unroll
    for (int n = 0; n < 4; ++n)
      bf[n] = *(const f16x8*)&Bs[wc * 64 + n * 16 + lr][lk * 8];
#pragma unroll
    for (int m = 0; m < 4; ++m)
#pragma unroll
      for (int n = 0; n < 4; ++n)
        acc[m][n] =
            __builtin_amdgcn_mfma_f32_16x16x32_f16(af[m], bf[n], acc[m][n], 0, 0, 0);
  }

  if (EPI == 0) {
#pragma unroll
    for (int m = 0; m < 4; ++m) {
      const int row = bm + wr * 64 + m * 16 + lk * 4;
#pragma unroll
      for (int n = 0; n < 4; ++n) {
        const int c = bn + wc * 64 + n * 16 + lr;
#pragma unroll
        for (int j = 0; j < 4; ++j)
          C[(size_t)(row + j) * N + c] = acc[m][n][j];
      }
    }
  } else {
    const int b = bm >> 10;
    const int s0 = bm & 1023;
    const int hd2 = by * 2 + wc;  // 0..31
    if (hd2 < 24) {
      // Q (hd2<16) or K: fused RMSNorm(64) + RoPE, fp16 store
      const bool isQ = (hd2 < 16);
      const float* nw = isQ ? qnw : knw;
      _Float16* dst = isQ ? qh : kh;
      const int ncols = isQ ? (NH * HD) : (NKV * HD);
      const int hcol = (isQ ? hd2 : (hd2 - 16)) * HD;
      float nwv[4];
#pragma unroll
      for (int n = 0; n < 4; ++n) nwv[n] = nw[n * 16 + lr];
#pragma unroll
      for (int m = 0; m < 4; ++m) {
#pragma unroll
        for (int j = 0; j < 4; ++j) {
          const int row = bm + wr * 64 + m * 16 + lk * 4 + j;
          float ss = 0.f;
#pragma unroll
          for (int n = 0; n < 4; ++n) ss += acc[m][n][j] * acc[m][n][j];
#pragma unroll
          for (int o = 1; o < 16; o <<= 1) ss += __shfl_xor(ss, o);
          const float rs = rsqrtf(ss * (1.0f / 64.0f) + 1e-6f);
          float y[4];
#pragma unroll
          for (int n = 0; n < 4; ++n) y[n] = acc[m][n][j] * rs * nwv[n];
          const size_t rb = (size_t)row * HD;
#pragma unroll
          for (int n = 0; n < 4; ++n) {
            const int d = n * 16 + lr;
            const float rot = (n < 2) ? -y[n + 2] : y[n - 2];
            dst[(size_t)row * ncols + hcol + d] =
                (_Float16)(y[n] * cosd[rb + d] + rot * sind[rb + d]);
          }
        }
      }
    } else {
      // V: fp16, stored TRANSPOSED: vT[((b*8+kv)*64+d)*S + s]
      const int kv = hd2 - 24;
#pragma unroll
      for (int m = 0; m < 4; ++m) {
        const int sbase = s0 + wr * 64 + m * 16 + lk * 4;
#pragma unroll
        for (int n = 0; n < 4; ++n) {
          const int d = n * 16 + lr;
          f16x4 pk;
#pragma unroll
          for (int j = 0; j < 4; ++j) pk[j] = (_Float16)acc[m][n][j];
          *(f16x4*)&vTp[((size_t)((b * NKV + kv) * HD + d)) * Ss + sbase] = pk;
        }
      }
    }
  }
}

// ------------- O-projection GEMM, BM=128 BN=64 BK=32 (grid 512 = 2/CU) -----
__global__ __launch_bounds__(256) void gemm_oproj(
    const _Float16* __restrict__ A, const _Float16* __restrict__ Bt,
    float* __restrict__ C, int N, int K) {
  __shared__ __align__(16) _Float16 As[128][32];
  __shared__ __align__(16) _Float16 Bs[64][32];
  const int tid = threadIdx.x;
  const int wave = tid >> 6, lane = tid & 63;
  const int lr = lane & 15, lk = lane >> 4;
  const int bm = blockIdx.x * 128;
  const int bn = blockIdx.y * 64;

  f32x4 acc[2][4] = {};

  const int ca0 = wave * 128 + lane;
  const int cb0 = wave * 64 + lane;
  const _Float16* Arow0 = A + (size_t)(bm + (ca0 >> 2)) * K + (ca0 & 3) * 8;
  const _Float16* Arow1 = A + (size_t)(bm + ((ca0 + 64) >> 2)) * K + ((ca0 + 64) & 3) * 8;
  const _Float16* Brow  = Bt + (size_t)(bn + (cb0 >> 2)) * K + (cb0 & 3) * 8;
  _Float16* lA0 = &As[0][0] + ca0 * 8;
  _Float16* lA1 = &As[0][0] + (ca0 + 64) * 8;
  _Float16* lB  = &Bs[0][0] + cb0 * 8;

  for (int k0 = 0; k0 < K; k0 += 32) {
    __syncthreads();
    gl_lds16(Arow0 + k0, lA0);
    gl_lds16(Arow1 + k0, lA1);
    gl_lds16(Brow + k0, lB);
    __syncthreads();
    f16x8 af[2], bf[4];
#pragma unroll
    for (int m = 0; m < 2; ++m)
      af[m] = *(const f16x8*)&As[wave * 32 + m * 16 + lr][lk * 8];
#pragma unroll
    for (int n = 0; n < 4; ++n)
      bf[n] = *(const f16x8*)&Bs[n * 16 + lr][lk * 8];
#pragma unroll
    for (int m = 0; m < 2; ++m)
#pragma unroll
      for (int n = 0; n < 4; ++n)
        acc[m][n] =
            __builtin_amdgcn_mfma_f32_16x16x32_f16(af[m], bf[n], acc[m][n], 0, 0, 0);
  }
#pragma unroll
  for (int m = 0; m < 2; ++m) {
    const int row = bm + wave * 32 + m * 16 + lk * 4;
#pragma unroll
    for (int n = 0; n < 4; ++n) {
      const int c = bn + n * 16 + lr;
#pragma unroll
      for (int j = 0; j < 4; ++j)
        C[(size_t)(row + j) * N + c] = acc[m][n][j];
    }
  }
}

// ------------- MFMA flash attention, fixed softmax max (m = 8) --------------
// QBLK=128, 8 waves (512 thr), wave w owns q-rows qt*128 + w*16 .. +15.
// One K/V staging round now feeds 8 waves (staging/barrier events ~halved vs
// QBLK=64). Per wave: tiles t < tdiag full, t == tdiag per-element masked,
// t > tdiag (only last tile, waves 0-3) -> zero weights, no MFMA.
// Fixed max: ||q||=||k||=8 after RMSNorm -> s in [-8,8];
// softmax = exp(s-8)/sum exp(s-8): no online max tracking.
__global__ __launch_bounds__(512) void attn_kernel(
    const _Float16* __restrict__ qh, const _Float16* __restrict__ kh,
    const _Float16* __restrict__ vT, float* __restrict__ attn,
    _Float16* __restrict__ ctxh) {
  __shared__ __align__(16) _Float16 Ks[64][72];
  __shared__ __align__(16) _Float16 Vs[64][72];
  __shared__ __align__(16) _Float16 Wh[8][16][72];
  const int qt = blockIdx.x, h = blockIdx.y, b = blockIdx.z;
  const int kvh = h >> 1;  // GQA groups = 2
  const int tid = threadIdx.x, wave = tid >> 6, lane = tid & 63;
  const int lr = lane & 15, lk = lane >> 4;
  const int q0 = qt * 128, qrow0 = q0 + wave * 16;
  const int tdiag = qrow0 >> 6;   // wave's diagonal k-tile
  const int tmax = 2 * qt + 1;    // block's last k-tile
  float* attn_bh = attn + (size_t)(b * NH + h) * Ss * Ss;

  // staging: one 16B chunk per thread (64 rows x 8 chunks = 512)
  const int sr = tid >> 3, sc = tid & 7;
  const _Float16* kb0 = kh + (size_t)(b * Ss) * (NKV * HD) + kvh * HD + sc * 8;
  const _Float16* vb0 = vT + (size_t)((b * NKV + kvh) * HD) * Ss + sc * 8;

  // Q A-fragments direct from global (once per block)
  const _Float16* qp = qh + (size_t)(b * Ss + qrow0 + lr) * (NH * HD) + h * HD + lk * 8;
  const f16x8 aq0 = *(const f16x8*)qp;
  const f16x8 aq1 = *(const f16x8*)(qp + 32);

  const float C1 = 0.18033688011112042f;  // 0.125 * log2(e)
  const float C2 = -11.541560327111707f;  // -8 * log2(e)

  // ---- pass A: softmax denominators only ----
  f16x8 pk = *(const f16x8*)(kb0 + (size_t)sr * (NKV * HD));
  float lsum[4] = {0.f, 0.f, 0.f, 0.f};
  for (int t = 0; t <= tmax; ++t) {
    __syncthreads();  // previous tile's LDS reads done
    *(f16x8*)&Ks[sr][sc * 8] = pk;
    if (t < tmax)
      pk = *(const f16x8*)(kb0 + (size_t)((t + 1) * 64 + sr) * (NKV * HD));
    __syncthreads();
    if (t > tdiag) continue;  // wave-uniform; both barriers already passed
    f32x4 acc[4] = {};
#pragma unroll
    for (int n = 0; n < 4; ++n) {
      f16x8 b0 = *(const f16x8*)&Ks[n * 16 + lr][lk * 8];
      acc[n] = __builtin_amdgcn_mfma_f32_16x16x32_f16(aq0, b0, acc[n], 0, 0, 0);
    }
#pragma unroll
    for (int n = 0; n < 4; ++n) {
      f16x8 b1 = *(const f16x8*)&Ks[n * 16 + lr][32 + lk * 8];
      acc[n] = __builtin_amdgcn_mfma_f32_16x16x32_f16(aq1, b1, acc[n], 0, 0, 0);
    }
    if (t < tdiag) {  // full tile: no mask
#pragma unroll
      for (int j = 0; j < 4; ++j)
#pragma unroll
        for (int n = 0; n < 4; ++n) lsum[j] += exp2f(fmaf(acc[n][j], C1, C2));
    } else {  // diagonal tile
#pragma unroll
      for (int j = 0; j < 4; ++j) {
        const int gr = qrow0 + lk * 4 + j;
#pragma unroll
        for (int n = 0; n < 4; ++n) {
          float p = exp2f(fmaf(acc[n][j], C1, C2));
          if (t * 64 + n * 16 + lr > gr) p = 0.f;
          lsum[j] += p;
        }
      }
    }
  }
  float linv[4];
#pragma unroll
  for (int j = 0; j < 4; ++j) {
#pragma unroll
    for (int o = 1; o < 16; o <<= 1) lsum[j] += __shfl_xor(lsum[j], o);
    linv[j] = 1.0f / lsum[j];
  }

  // ---- pass B: recompute scores, write weights once, PV accumulate ----
  pk = *(const f16x8*)(kb0 + (size_t)sr * (NKV * HD));
  f16x8 pv = *(const f16x8*)(vb0 + (size_t)sr * Ss);
  f32x4 acc2[4] = {};
  const int wr = lane >> 2;
  const int wc0 = (lane & 3) * 16;
  for (int t = 0; t <= tmax; ++t) {
    __syncthreads();
    *(f16x8*)&Ks[sr][sc * 8] = pk;
    *(f16x8*)&Vs[sr][sc * 8] = pv;
    if (t < tmax) {
      pk = *(const f16x8*)(kb0 + (size_t)((t + 1) * 64 + sr) * (NKV * HD));
      pv = *(const f16x8*)(vb0 + (size_t)sr * Ss + (t + 1) * 64);
    }
    __syncthreads();
    if (t > tdiag) {
      // beyond this wave's diagonal: weights are zero (still block's k-range)
      const float4 z4 = make_float4(0.f, 0.f, 0.f, 0.f);
#pragma unroll
      for (int i2 = 0; i2 < 4; ++i2)
        *(float4*)&attn_bh[(size_t)(qrow0 + wr) * Ss + t * 64 + wc0 + i2 * 4] = z4;
      continue;
    }
    f32x4 acc[4] = {};
#pragma unroll
    for (int n = 0; n < 4; ++n) {
      f16x8 b0 = *(const f16x8*)&Ks[n * 16 + lr][lk * 8];
      acc[n] = __builtin_amdgcn_mfma_f32_16x16x32_f16(aq0, b0, acc[n], 0, 0, 0);
    }
#pragma unroll
    for (int n = 0; n < 4; ++n) {
      f16x8 b1 = *(const f16x8*)&Ks[n * 16 + lr][32 + lk * 8];
      acc[n] = __builtin_amdgcn_mfma_f32_16x16x32_f16(aq1, b1, acc[n], 0, 0, 0);
    }
    if (t < tdiag) {
#pragma unroll
      for (int j = 0; j < 4; ++j)
#pragma unroll
        for (int n = 0; n < 4; ++n) {
          const float w = exp2f(fmaf(acc[n][j], C1, C2)) * linv[j];
          Wh[wave][lk * 4 + j][n * 16 + lr] = (_Float16)w;
        }
    } else {
#pragma unroll
      for (int j = 0; j < 4; ++j) {
        const int gr = qrow0 + lk * 4 + j;
#pragma unroll
        for (int n = 0; n < 4; ++n) {
          float w = exp2f(fmaf(acc[n][j], C1, C2)) * linv[j];
          if (t * 64 + n * 16 + lr > gr) w = 0.f;
          Wh[wave][lk * 4 + j][n * 16 + lr] = (_Float16)w;
        }
      }
    }
    // PV: A = Wh rows (own 16 q-rows), B = V^T tile (in-wave DS ordering)
#pragma unroll
    for (int kc = 0; kc < 2; ++kc) {
      f16x8 aw = *(const f16x8*)&Wh[wave][lr][kc * 32 + lk * 8];
#pragma unroll
      for (int n = 0; n < 4; ++n) {
        f16x8 bv = *(const f16x8*)&Vs[n * 16 + lr][kc * 32 + lk * 8];
        acc2[n] = __builtin_amdgcn_mfma_f32_16x16x32_f16(aw, bv, acc2[n], 0, 0, 0);
      }
    }
    // weights -> HBM via Wh (coalesced float4, cached stores)
#pragma unroll
    for (int i2 = 0; i2 < 4; ++i2) {
      f16x4 hv = *(const f16x4*)&Wh[wave][wr][wc0 + i2 * 4];
      *(float4*)&attn_bh[(size_t)(qrow0 + wr) * Ss + t * 64 + wc0 + i2 * 4] =
          make_float4((float)hv[0], (float)hv[1], (float)hv[2], (float)hv[3]);
    }
  }

  // zero the fully-masked tiles (beyond the block's k-range)
  for (int t = tmax + 1; t < 16; ++t)
    for (int idx = tid; idx < 2048; idx += 512) {
      int r = idx >> 4, c4 = (idx & 15) * 4;
      *(float4*)&attn_bh[(size_t)(q0 + r) * Ss + t * 64 + c4] =
          make_float4(0.f, 0.f, 0.f, 0.f);
    }

  // ctx store (fp16)
#pragma unroll
  for (int n = 0; n < 4; ++n)
#pragma unroll
    for (int j = 0; j < 4; ++j)
      ctxh[(size_t)(b * Ss + qrow0 + lk * 4 + j) * (NH * HD) + h * HD + n * 16 + lr] =
          (_Float16)acc2[n][j];
}

// ---------------- launch ----------------
extern "C" void kernel_launch(void* const* d_in, const int* in_sizes, int n_in,
                              void* d_out, int out_size, void* d_ws, size_t ws_size,
                              hipStream_t stream) {
  const float* hs   = (const float*)d_in[0];
  const float* cosb = (const float*)d_in[1];
  const float* sinb = (const float*)d_in[2];
  // d_in[3] attention_mask: causal, reproduced analytically
  const float* Wq = (const float*)d_in[4];
  const float* Wk = (const float*)d_in[5];
  const float* Wv = (const float*)d_in[6];
  const float* Wo = (const float*)d_in[7];
  const float* qw = (const float*)d_in[8];
  const float* kw = (const float*)d_in[9];

  char* ws = (char*)d_ws;
  _Float16* Xh    = (_Float16*)(ws);             // 4096x1024 fp16 (8 MB)
  _Float16* Wqkvh = (_Float16*)(ws + 8388608);   // 2048x1024 fp16 (4 MB) Q|K|V
  _Float16* Woh   = (_Float16*)(ws + 12582912);  // 1024x1024 fp16 (2 MB)
  _Float16* qh    = (_Float16*)(ws + 14680064);  // 4096x1024 fp16 (8 MB)
  _Float16* kh    = (_Float16*)(ws + 23068672);  // 4096x512  fp16 (4 MB)
  _Float16* vT    = (_Float16*)(ws + 27262976);  // [4*8*64][1024] (4 MB)
  _Float16* ctxh  = (_Float16*)(ws + 31457280);  // 4096x1024 fp16 (8 MB)

  float* out  = (float*)d_out;
  float* attn = out + (size_t)Bb * Ss * HID;

  f2h_all<<<7168, 256, 0, stream>>>(hs, Wq, Wk, Wv, Wo, Xh, Wqkvh,
                                    Wqkvh + 1048576, Wqkvh + 1572864, Woh);

  // fused QKV projection + RMSNorm/RoPE/V-transpose epilogues (128x128 tiles)
  gemm128<1><<<dim3(32, 16), 256, 0, stream>>>(
      Xh, Wqkvh, nullptr, qh, kh, vT, qw, kw, cosb, sinb, 2048, 1024);

  attn_kernel<<<dim3(8, 16, 4), 512, 0, stream>>>(qh, kh, vT, attn, ctxh);

  // O-projection
  gemm_oproj<<<dim3(32, 16), 256, 0, stream>>>(ctxh, Woh, out, 1024, 1024);
}

// Round 9
// 180.897 us; speedup vs baseline: 1.0223x; 1.0223x over previous
//
#include <hip/hip_runtime.h>
#include <hip/hip_fp16.h>

#define Bb 4
#define Ss 1024
#define HID 1024
#define NH 16
#define NKV 8
#define HD 64

typedef _Float16 f16x8 __attribute__((ext_vector_type(8)));
typedef _Float16 f16x4 __attribute__((ext_vector_type(4)));
typedef float f32x4 __attribute__((ext_vector_type(4)));

typedef const __attribute__((address_space(1))) unsigned int gu32;
typedef __attribute__((address_space(3))) unsigned int lu32;

__device__ __forceinline__ void gl_lds16(const _Float16* g, _Float16* l) {
  __builtin_amdgcn_global_load_lds((gu32*)g, (lu32*)l, 16, 0, 0);
}

// ------------- fused fp32 -> fp16 conversion (all 5 tensors, one launch) ----
__global__ __launch_bounds__(256) void f2h_all(
    const float* __restrict__ a0, const float* __restrict__ a1,
    const float* __restrict__ a2, const float* __restrict__ a3,
    const float* __restrict__ a4, _Float16* __restrict__ o0,
    _Float16* __restrict__ o1, _Float16* __restrict__ o2,
    _Float16* __restrict__ o3, _Float16* __restrict__ o4) {
  const int bid = blockIdx.x;
  const float* src;
  _Float16* dst;
  int base;
  if (bid < 4096)      { src = a0; dst = o0; base = bid; }
  else if (bid < 5120) { src = a1; dst = o1; base = bid - 4096; }
  else if (bid < 5632) { src = a2; dst = o2; base = bid - 5120; }
  else if (bid < 6144) { src = a3; dst = o3; base = bid - 5632; }
  else                 { src = a4; dst = o4; base = bid - 6144; }
  const int i = base * 1024 + threadIdx.x * 4;
  const float4 v = *(const float4*)(src + i);
  f16x4 h;
  h[0] = (_Float16)v.x; h[1] = (_Float16)v.y;
  h[2] = (_Float16)v.z; h[3] = (_Float16)v.w;
  *(f16x4*)(dst + i) = h;
}

// ------------- MFMA GEMM, BM=BN=128 BK=32 (m97 structure), QKV epilogue ----
template <int EPI>
__global__ __launch_bounds__(256) void gemm128(
    const _Float16* __restrict__ A, const _Float16* __restrict__ Bt,
    float* __restrict__ C, _Float16* __restrict__ qh, _Float16* __restrict__ kh,
    _Float16* __restrict__ vTp, const float* __restrict__ qnw,
    const float* __restrict__ knw, const float* __restrict__ cosd,
    const float* __restrict__ sind, int N, int K) {
  __shared__ __align__(16) _Float16 As[128][32];
  __shared__ __align__(16) _Float16 Bs[128][32];
  const int tid = threadIdx.x;
  const int wave = tid >> 6, lane = tid & 63;
  const int lr = lane & 15, lk = lane >> 4;
  const int wr = wave >> 1, wc = wave & 1;
  const int bm = blockIdx.x * 128;
  const int by = blockIdx.y;
  const int bn = by * 128;

  f32x4 acc[4][4] = {};

  const int ca0 = wave * 128 + lane;
  const _Float16* Arow0 = A + (size_t)(bm + (ca0 >> 2)) * K + (ca0 & 3) * 8;
  const _Float16* Arow1 = A + (size_t)(bm + ((ca0 + 64) >> 2)) * K + ((ca0 + 64) & 3) * 8;
  const _Float16* Brow0 = Bt + (size_t)(bn + (ca0 >> 2)) * K + (ca0 & 3) * 8;
  const _Float16* Brow1 = Bt + (size_t)(bn + ((ca0 + 64) >> 2)) * K + ((ca0 + 64) & 3) * 8;
  _Float16* lA0 = &As[0][0] + ca0 * 8;
  _Float16* lA1 = &As[0][0] + (ca0 + 64) * 8;
  _Float16* lB0 = &Bs[0][0] + ca0 * 8;
  _Float16* lB1 = &Bs[0][0] + (ca0 + 64) * 8;

  for (int k0 = 0; k0 < K; k0 += 32) {
    __syncthreads();
    gl_lds16(Arow0 + k0, lA0);
    gl_lds16(Arow1 + k0, lA1);
    gl_lds16(Brow0 + k0, lB0);
    gl_lds16(Brow1 + k0, lB1);
    __syncthreads();
    f16x8 af[4], bf[4];
#pragma unroll
    for (int m = 0; m < 4; ++m)
      af[m] = *(const f16x8*)&As[wr * 64 + m * 16 + lr][lk * 8];
#pragma unroll
    for (int n = 0; n < 4; ++n)
      bf[n] = *(const f16x8*)&Bs[wc * 64 + n * 16 + lr][lk * 8];
#pragma unroll
    for (int m = 0; m < 4; ++m)
#pragma unroll
      for (int n = 0; n < 4; ++n)
        acc[m][n] =
            __builtin_amdgcn_mfma_f32_16x16x32_f16(af[m], bf[n], acc[m][n], 0, 0, 0);
  }

  if (EPI == 0) {
#pragma unroll
    for (int m = 0; m < 4; ++m) {
      const int row = bm + wr * 64 + m * 16 + lk * 4;
#pragma unroll
      for (int n = 0; n < 4; ++n) {
        const int c = bn + wc * 64 + n * 16 + lr;
#pragma unroll
        for (int j = 0; j < 4; ++j)
          C[(size_t)(row + j) * N + c] = acc[m][n][j];
      }
    }
  } else {
    const int b = bm >> 10;
    const int s0 = bm & 1023;
    const int hd2 = by * 2 + wc;  // 0..31
    if (hd2 < 24) {
      const bool isQ = (hd2 < 16);
      const float* nw = isQ ? qnw : knw;
      _Float16* dst = isQ ? qh : kh;
      const int ncols = isQ ? (NH * HD) : (NKV * HD);
      const int hcol = (isQ ? hd2 : (hd2 - 16)) * HD;
      float nwv[4];
#pragma unroll
      for (int n = 0; n < 4; ++n) nwv[n] = nw[n * 16 + lr];
#pragma unroll
      for (int m = 0; m < 4; ++m) {
#pragma unroll
        for (int j = 0; j < 4; ++j) {
          const int row = bm + wr * 64 + m * 16 + lk * 4 + j;
          float ss = 0.f;
#pragma unroll
          for (int n = 0; n < 4; ++n) ss += acc[m][n][j] * acc[m][n][j];
#pragma unroll
          for (int o = 1; o < 16; o <<= 1) ss += __shfl_xor(ss, o);
          const float rs = rsqrtf(ss * (1.0f / 64.0f) + 1e-6f);
          float y[4];
#pragma unroll
          for (int n = 0; n < 4; ++n) y[n] = acc[m][n][j] * rs * nwv[n];
          const size_t rb = (size_t)row * HD;
#pragma unroll
          for (int n = 0; n < 4; ++n) {
            const int d = n * 16 + lr;
            const float rot = (n < 2) ? -y[n + 2] : y[n - 2];
            dst[(size_t)row * ncols + hcol + d] =
                (_Float16)(y[n] * cosd[rb + d] + rot * sind[rb + d]);
          }
        }
      }
    } else {
      const int kv = hd2 - 24;
#pragma unroll
      for (int m = 0; m < 4; ++m) {
        const int sbase = s0 + wr * 64 + m * 16 + lk * 4;
#pragma unroll
        for (int n = 0; n < 4; ++n) {
          const int d = n * 16 + lr;
          f16x4 pk;
#pragma unroll
          for (int j = 0; j < 4; ++j) pk[j] = (_Float16)acc[m][n][j];
          *(f16x4*)&vTp[((size_t)((b * NKV + kv) * HD + d)) * Ss + sbase] = pk;
        }
      }
    }
  }
}

// ------------- O-projection GEMM, BM=128 BN=64 BK=32 (grid 512 = 2/CU) -----
__global__ __launch_bounds__(256) void gemm_oproj(
    const _Float16* __restrict__ A, const _Float16* __restrict__ Bt,
    float* __restrict__ C, int N, int K) {
  __shared__ __align__(16) _Float16 As[128][32];
  __shared__ __align__(16) _Float16 Bs[64][32];
  const int tid = threadIdx.x;
  const int wave = tid >> 6, lane = tid & 63;
  const int lr = lane & 15, lk = lane >> 4;
  const int bm = blockIdx.x * 128;
  const int bn = blockIdx.y * 64;

  f32x4 acc[2][4] = {};

  const int ca0 = wave * 128 + lane;
  const int cb0 = wave * 64 + lane;
  const _Float16* Arow0 = A + (size_t)(bm + (ca0 >> 2)) * K + (ca0 & 3) * 8;
  const _Float16* Arow1 = A + (size_t)(bm + ((ca0 + 64) >> 2)) * K + ((ca0 + 64) & 3) * 8;
  const _Float16* Brow  = Bt + (size_t)(bn + (cb0 >> 2)) * K + (cb0 & 3) * 8;
  _Float16* lA0 = &As[0][0] + ca0 * 8;
  _Float16* lA1 = &As[0][0] + (ca0 + 64) * 8;
  _Float16* lB  = &Bs[0][0] + cb0 * 8;

  for (int k0 = 0; k0 < K; k0 += 32) {
    __syncthreads();
    gl_lds16(Arow0 + k0, lA0);
    gl_lds16(Arow1 + k0, lA1);
    gl_lds16(Brow + k0, lB);
    __syncthreads();
    f16x8 af[2], bf[4];
#pragma unroll
    for (int m = 0; m < 2; ++m)
      af[m] = *(const f16x8*)&As[wave * 32 + m * 16 + lr][lk * 8];
#pragma unroll
    for (int n = 0; n < 4; ++n)
      bf[n] = *(const f16x8*)&Bs[n * 16 + lr][lk * 8];
#pragma unroll
    for (int m = 0; m < 2; ++m)
#pragma unroll
      for (int n = 0; n < 4; ++n)
        acc[m][n] =
            __builtin_amdgcn_mfma_f32_16x16x32_f16(af[m], bf[n], acc[m][n], 0, 0, 0);
  }
#pragma unroll
  for (int m = 0; m < 2; ++m) {
    const int row = bm + wave * 32 + m * 16 + lk * 4;
#pragma unroll
    for (int n = 0; n < 4; ++n) {
      const int c = bn + n * 16 + lr;
#pragma unroll
      for (int j = 0; j < 4; ++j)
        C[(size_t)(row + j) * N + c] = acc[m][n][j];
    }
  }
}

// ------------- MFMA flash attention, diagonal-paired Q-tiles ----------------
// Block (p,h,b), p in 0..7, handles Q-tiles qa=p (light) and qb=15-p (heavy):
// exactly 17 tile-computes per pass per block -> perfectly uniform load.
// K/V staged ONCE per k-tile, shared by both Q-tiles. Fixed softmax max
// (||q||=||k||=8): softmax = exp(s-8)/sum exp(s-8), no online max.
// R6-proven 2-barrier staging: 256 threads stage TWO rows each (sr, sr+32) --
// R8's bug was staging only rows 0..31 of the 64-row tile.
__global__ __launch_bounds__(256) void attn_kernel(
    const _Float16* __restrict__ qh, const _Float16* __restrict__ kh,
    const _Float16* __restrict__ vT, float* __restrict__ attn,
    _Float16* __restrict__ ctxh) {
  __shared__ __align__(16) _Float16 Ks[64][72];
  __shared__ __align__(16) _Float16 Vs[64][72];
  __shared__ __align__(16) _Float16 Wh[4][16][72];
  const int p = blockIdx.x, h = blockIdx.y, b = blockIdx.z;
  const int kvh = h >> 1;  // GQA groups = 2
  const int tid = threadIdx.x, wave = tid >> 6, lane = tid & 63;
  const int lr = lane & 15, lk = lane >> 4;
  const int qa = p, qb = 15 - p;          // paired q-tiles
  const int qrowA = qa * 64 + wave * 16;  // this wave's rows in tile A
  const int qrowB = qb * 64 + wave * 16;
  const int tlast = qb;                   // staged k-tiles: 0..tlast
  float* attn_bh = attn + (size_t)(b * NH + h) * Ss * Ss;

  // staging: thread covers rows sr and sr+32 at 16B chunk sc
  const int sr = tid >> 3, sc = tid & 7;
  const _Float16* kb0 = kh + (size_t)(b * Ss) * (NKV * HD) + kvh * HD + sc * 8;
  const _Float16* vb0 = vT + (size_t)((b * NKV + kvh) * HD) * Ss + sc * 8;

  // Q A-fragments for both tiles, direct from global (once per block)
  const _Float16* qpA =
      qh + (size_t)(b * Ss + qrowA + lr) * (NH * HD) + h * HD + lk * 8;
  const _Float16* qpB =
      qh + (size_t)(b * Ss + qrowB + lr) * (NH * HD) + h * HD + lk * 8;
  const f16x8 aqA0 = *(const f16x8*)qpA;
  const f16x8 aqA1 = *(const f16x8*)(qpA + 32);
  const f16x8 aqB0 = *(const f16x8*)qpB;
  const f16x8 aqB1 = *(const f16x8*)(qpB + 32);

  const float C1 = 0.18033688011112042f;  // 0.125 * log2(e)
  const float C2 = -11.541560327111707f;  // -8 * log2(e)

  auto qk_tile = [&](const f16x8& a0, const f16x8& a1, f32x4* acc) {
#pragma unroll
    for (int n = 0; n < 4; ++n) {
      f16x8 b0 = *(const f16x8*)&Ks[n * 16 + lr][lk * 8];
      acc[n] = __builtin_amdgcn_mfma_f32_16x16x32_f16(a0, b0, acc[n], 0, 0, 0);
    }
#pragma unroll
    for (int n = 0; n < 4; ++n) {
      f16x8 b1 = *(const f16x8*)&Ks[n * 16 + lr][32 + lk * 8];
      acc[n] = __builtin_amdgcn_mfma_f32_16x16x32_f16(a1, b1, acc[n], 0, 0, 0);
    }
  };

  // ---- pass A: softmax denominators for both q-tiles ----
  float lsumA[4] = {0.f, 0.f, 0.f, 0.f};
  float lsumB[4] = {0.f, 0.f, 0.f, 0.f};
  {
    f16x8 pk0 = *(const f16x8*)(kb0 + (size_t)sr * (NKV * HD));
    f16x8 pk1 = *(const f16x8*)(kb0 + (size_t)(sr + 32) * (NKV * HD));
    for (int t = 0; t <= tlast; ++t) {
      __syncthreads();
      *(f16x8*)&Ks[sr][sc * 8] = pk0;
      *(f16x8*)&Ks[sr + 32][sc * 8] = pk1;
      if (t < tlast) {
        pk0 = *(const f16x8*)(kb0 + (size_t)((t + 1) * 64 + sr) * (NKV * HD));
        pk1 = *(const f16x8*)(kb0 + (size_t)((t + 1) * 64 + sr + 32) * (NKV * HD));
      }
      __syncthreads();
      // heavy tile B: active on all staged tiles
      {
        f32x4 acc[4] = {};
        qk_tile(aqB0, aqB1, acc);
        if (t < qb) {
#pragma unroll
          for (int j = 0; j < 4; ++j)
#pragma unroll
            for (int n = 0; n < 4; ++n) lsumB[j] += exp2f(fmaf(acc[n][j], C1, C2));
        } else {
#pragma unroll
          for (int j = 0; j < 4; ++j) {
            const int gr = qrowB + lk * 4 + j;
#pragma unroll
            for (int n = 0; n < 4; ++n) {
              float pw = exp2f(fmaf(acc[n][j], C1, C2));
              if (t * 64 + n * 16 + lr > gr) pw = 0.f;
              lsumB[j] += pw;
            }
          }
        }
      }
      // light tile A: active while t <= qa
      if (t <= qa) {
        f32x4 acc[4] = {};
        qk_tile(aqA0, aqA1, acc);
        if (t < qa) {
#pragma unroll
          for (int j = 0; j < 4; ++j)
#pragma unroll
            for (int n = 0; n < 4; ++n) lsumA[j] += exp2f(fmaf(acc[n][j], C1, C2));
        } else {
#pragma unroll
          for (int j = 0; j < 4; ++j) {
            const int gr = qrowA + lk * 4 + j;
#pragma unroll
            for (int n = 0; n < 4; ++n) {
              float pw = exp2f(fmaf(acc[n][j], C1, C2));
              if (t * 64 + n * 16 + lr > gr) pw = 0.f;
              lsumA[j] += pw;
            }
          }
        }
      }
    }
  }
  float linvA[4], linvB[4];
#pragma unroll
  for (int j = 0; j < 4; ++j) {
#pragma unroll
    for (int o = 1; o < 16; o <<= 1) {
      lsumA[j] += __shfl_xor(lsumA[j], o);
      lsumB[j] += __shfl_xor(lsumB[j], o);
    }
    linvA[j] = 1.0f / lsumA[j];
    linvB[j] = 1.0f / lsumB[j];
  }

  // ---- pass B: recompute scores, weights -> HBM once, PV accumulate ----
  const int wr = lane >> 2;
  const int wc0 = (lane & 3) * 16;
  f32x4 accA2[4] = {}, accB2[4] = {};

  auto w_pv_store = [&](int t, int qrow0, const float* linv, bool diag,
                        f32x4* accS, f32x4* acc2) {
    if (!diag) {
#pragma unroll
      for (int j = 0; j < 4; ++j)
#pragma unroll
        for (int n = 0; n < 4; ++n) {
          const float w = exp2f(fmaf(accS[n][j], C1, C2)) * linv[j];
          Wh[wave][lk * 4 + j][n * 16 + lr] = (_Float16)w;
        }
    } else {
#pragma unroll
      for (int j = 0; j < 4; ++j) {
        const int gr = qrow0 + lk * 4 + j;
#pragma unroll
        for (int n = 0; n < 4; ++n) {
          float w = exp2f(fmaf(accS[n][j], C1, C2)) * linv[j];
          if (t * 64 + n * 16 + lr > gr) w = 0.f;
          Wh[wave][lk * 4 + j][n * 16 + lr] = (_Float16)w;
        }
      }
    }
    // PV MFMA (in-wave DS ordering on Wh)
#pragma unroll
    for (int kc = 0; kc < 2; ++kc) {
      f16x8 aw = *(const f16x8*)&Wh[wave][lr][kc * 32 + lk * 8];
#pragma unroll
      for (int n = 0; n < 4; ++n) {
        f16x8 bv = *(const f16x8*)&Vs[n * 16 + lr][kc * 32 + lk * 8];
        acc2[n] = __builtin_amdgcn_mfma_f32_16x16x32_f16(aw, bv, acc2[n], 0, 0, 0);
      }
    }
    // weights -> HBM (coalesced float4)
#pragma unroll
    for (int i2 = 0; i2 < 4; ++i2) {
      f16x4 hv = *(const f16x4*)&Wh[wave][wr][wc0 + i2 * 4];
      *(float4*)&attn_bh[(size_t)(qrow0 + wr) * Ss + t * 64 + wc0 + i2 * 4] =
          make_float4((float)hv[0], (float)hv[1], (float)hv[2], (float)hv[3]);
    }
  };
  auto zero_store = [&](int t, int qrow0) {
    const float4 z4 = make_float4(0.f, 0.f, 0.f, 0.f);
#pragma unroll
    for (int i2 = 0; i2 < 4; ++i2)
      *(float4*)&attn_bh[(size_t)(qrow0 + wr) * Ss + t * 64 + wc0 + i2 * 4] = z4;
  };

  {
    f16x8 pk0 = *(const f16x8*)(kb0 + (size_t)sr * (NKV * HD));
    f16x8 pk1 = *(const f16x8*)(kb0 + (size_t)(sr + 32) * (NKV * HD));
    f16x8 pv0 = *(const f16x8*)(vb0 + (size_t)sr * Ss);
    f16x8 pv1 = *(const f16x8*)(vb0 + (size_t)(sr + 32) * Ss);
    for (int t = 0; t <= tlast; ++t) {
      __syncthreads();
      *(f16x8*)&Ks[sr][sc * 8] = pk0;
      *(f16x8*)&Ks[sr + 32][sc * 8] = pk1;
      *(f16x8*)&Vs[sr][sc * 8] = pv0;
      *(f16x8*)&Vs[sr + 32][sc * 8] = pv1;
      if (t < tlast) {
        pk0 = *(const f16x8*)(kb0 + (size_t)((t + 1) * 64 + sr) * (NKV * HD));
        pk1 = *(const f16x8*)(kb0 + (size_t)((t + 1) * 64 + sr + 32) * (NKV * HD));
        pv0 = *(const f16x8*)(vb0 + (size_t)sr * Ss + (t + 1) * 64);
        pv1 = *(const f16x8*)(vb0 + (size_t)(sr + 32) * Ss + (t + 1) * 64);
      }
      __syncthreads();
      // heavy tile B
      {
        f32x4 acc[4] = {};
        qk_tile(aqB0, aqB1, acc);
        w_pv_store(t, qrowB, linvB, t == qb, acc, accB2);
      }
      // light tile A (or its mandatory zero weights)
      if (t <= qa) {
        f32x4 acc[4] = {};
        qk_tile(aqA0, aqA1, acc);
        w_pv_store(t, qrowA, linvA, t == qa, acc, accA2);
      } else {
        zero_store(t, qrowA);
      }
    }
  }

  // tail: zero weights beyond the staged range
  for (int t = tlast + 1; t < 16; ++t) {
    zero_store(t, qrowA);
    zero_store(t, qrowB);
  }

  // ctx stores (fp16) for both q-tiles
#pragma unroll
  for (int n = 0; n < 4; ++n)
#pragma unroll
    for (int j = 0; j < 4; ++j) {
      ctxh[(size_t)(b * Ss + qrowA + lk * 4 + j) * (NH * HD) + h * HD + n * 16 + lr] =
          (_Float16)accA2[n][j];
      ctxh[(size_t)(b * Ss + qrowB + lk * 4 + j) * (NH * HD) + h * HD + n * 16 + lr] =
          (_Float16)accB2[n][j];
    }
}

// ---------------- launch ----------------
extern "C" void kernel_launch(void* const* d_in, const int* in_sizes, int n_in,
                              void* d_out, int out_size, void* d_ws, size_t ws_size,
                              hipStream_t stream) {
  const float* hs   = (const float*)d_in[0];
  const float* cosb = (const float*)d_in[1];
  const float* sinb = (const float*)d_in[2];
  // d_in[3] attention_mask: causal, reproduced analytically
  const float* Wq = (const float*)d_in[4];
  const float* Wk = (const float*)d_in[5];
  const float* Wv = (const float*)d_in[6];
  const float* Wo = (const float*)d_in[7];
  const float* qw = (const float*)d_in[8];
  const float* kw = (const float*)d_in[9];

  char* ws = (char*)d_ws;
  _Float16* Xh    = (_Float16*)(ws);             // 4096x1024 fp16 (8 MB)
  _Float16* Wqkvh = (_Float16*)(ws + 8388608);   // 2048x1024 fp16 (4 MB) Q|K|V
  _Float16* Woh   = (_Float16*)(ws + 12582912);  // 1024x1024 fp16 (2 MB)
  _Float16* qh    = (_Float16*)(ws + 14680064);  // 4096x1024 fp16 (8 MB)
  _Float16* kh    = (_Float16*)(ws + 23068672);  // 4096x512  fp16 (4 MB)
  _Float16* vT    = (_Float16*)(ws + 27262976);  // [4*8*64][1024] (4 MB)
  _Float16* ctxh  = (_Float16*)(ws + 31457280);  // 4096x1024 fp16 (8 MB)

  float* out  = (float*)d_out;
  float* attn = out + (size_t)Bb * Ss * HID;

  f2h_all<<<7168, 256, 0, stream>>>(hs, Wq, Wk, Wv, Wo, Xh, Wqkvh,
                                    Wqkvh + 1048576, Wqkvh + 1572864, Woh);

  // fused QKV projection + RMSNorm/RoPE/V-transpose epilogues (128x128 tiles)
  gemm128<1><<<dim3(32, 16), 256, 0, stream>>>(
      Xh, Wqkvh, nullptr, qh, kh, vT, qw, kw, cosb, sinb, 2048, 1024);

  // diagonal-paired attention: block p handles q-tiles {p, 15-p}
  attn_kernel<<<dim3(8, 16, 4), 256, 0, stream>>>(qh, kh, vT, attn, ctxh);

  // O-projection
  gemm_oproj<<<dim3(32, 16), 256, 0, stream>>>(ctxh, Woh, out, 1024, 1024);
}

// Round 10
// 149.190 us; speedup vs baseline: 1.2396x; 1.2125x over previous
//
#include <hip/hip_runtime.h>
#include <hip/hip_fp16.h>

#define Bb 4
#define Ss 1024
#define HID 1024
#define NH 16
#define NKV 8
#define HD 64

typedef _Float16 f16x8 __attribute__((ext_vector_type(8)));
typedef _Float16 f16x4 __attribute__((ext_vector_type(4)));
typedef float f32x4 __attribute__((ext_vector_type(4)));

typedef const __attribute__((address_space(1))) unsigned int gu32;
typedef __attribute__((address_space(3))) unsigned int lu32;

__device__ __forceinline__ void gl_lds16(const _Float16* g, _Float16* l) {
  __builtin_amdgcn_global_load_lds((gu32*)g, (lu32*)l, 16, 0, 0);
}

// ------------- fused fp32 -> fp16 conversion (all 5 tensors, one launch) ----
__global__ __launch_bounds__(256) void f2h_all(
    const float* __restrict__ a0, const float* __restrict__ a1,
    const float* __restrict__ a2, const float* __restrict__ a3,
    const float* __restrict__ a4, _Float16* __restrict__ o0,
    _Float16* __restrict__ o1, _Float16* __restrict__ o2,
    _Float16* __restrict__ o3, _Float16* __restrict__ o4) {
  const int bid = blockIdx.x;
  const float* src;
  _Float16* dst;
  int base;
  if (bid < 4096)      { src = a0; dst = o0; base = bid; }
  else if (bid < 5120) { src = a1; dst = o1; base = bid - 4096; }
  else if (bid < 5632) { src = a2; dst = o2; base = bid - 5120; }
  else if (bid < 6144) { src = a3; dst = o3; base = bid - 5632; }
  else                 { src = a4; dst = o4; base = bid - 6144; }
  const int i = base * 1024 + threadIdx.x * 4;
  const float4 v = *(const float4*)(src + i);
  f16x4 h;
  h[0] = (_Float16)v.x; h[1] = (_Float16)v.y;
  h[2] = (_Float16)v.z; h[3] = (_Float16)v.w;
  *(f16x4*)(dst + i) = h;
}

// ------------- MFMA GEMM, BM=BN=128 BK=32 (m97 structure), QKV epilogue ----
template <int EPI>
__global__ __launch_bounds__(256) void gemm128(
    const _Float16* __restrict__ A, const _Float16* __restrict__ Bt,
    float* __restrict__ C, _Float16* __restrict__ qh, _Float16* __restrict__ kh,
    _Float16* __restrict__ vTp, const float* __restrict__ qnw,
    const float* __restrict__ knw, const float* __restrict__ cosd,
    const float* __restrict__ sind, int N, int K) {
  __shared__ __align__(16) _Float16 As[128][32];
  __shared__ __align__(16) _Float16 Bs[128][32];
  const int tid = threadIdx.x;
  const int wave = tid >> 6, lane = tid & 63;
  const int lr = lane & 15, lk = lane >> 4;
  const int wr = wave >> 1, wc = wave & 1;
  const int bm = blockIdx.x * 128;
  const int by = blockIdx.y;
  const int bn = by * 128;

  f32x4 acc[4][4] = {};

  const int ca0 = wave * 128 + lane;
  const _Float16* Arow0 = A + (size_t)(bm + (ca0 >> 2)) * K + (ca0 & 3) * 8;
  const _Float16* Arow1 = A + (size_t)(bm + ((ca0 + 64) >> 2)) * K + ((ca0 + 64) & 3) * 8;
  const _Float16* Brow0 = Bt + (size_t)(bn + (ca0 >> 2)) * K + (ca0 & 3) * 8;
  const _Float16* Brow1 = Bt + (size_t)(bn + ((ca0 + 64) >> 2)) * K + ((ca0 + 64) & 3) * 8;
  _Float16* lA0 = &As[0][0] + ca0 * 8;
  _Float16* lA1 = &As[0][0] + (ca0 + 64) * 8;
  _Float16* lB0 = &Bs[0][0] + ca0 * 8;
  _Float16* lB1 = &Bs[0][0] + (ca0 + 64) * 8;

  for (int k0 = 0; k0 < K; k0 += 32) {
    __syncthreads();
    gl_lds16(Arow0 + k0, lA0);
    gl_lds16(Arow1 + k0, lA1);
    gl_lds16(Brow0 + k0, lB0);
    gl_lds16(Brow1 + k0, lB1);
    __syncthreads();
    f16x8 af[4], bf[4];
#pragma unroll
    for (int m = 0; m < 4; ++m)
      af[m] = *(const f16x8*)&As[wr * 64 + m * 16 + lr][lk * 8];
#pragma unroll
    for (int n = 0; n < 4; ++n)
      bf[n] = *(const f16x8*)&Bs[wc * 64 + n * 16 + lr][lk * 8];
#pragma unroll
    for (int m = 0; m < 4; ++m)
#pragma unroll
      for (int n = 0; n < 4; ++n)
        acc[m][n] =
            __builtin_amdgcn_mfma_f32_16x16x32_f16(af[m], bf[n], acc[m][n], 0, 0, 0);
  }

  if (EPI == 0) {
#pragma unroll
    for (int m = 0; m < 4; ++m) {
      const int row = bm + wr * 64 + m * 16 + lk * 4;
#pragma unroll
      for (int n = 0; n < 4; ++n) {
        const int c = bn + wc * 64 + n * 16 + lr;
#pragma unroll
        for (int j = 0; j < 4; ++j)
          C[(size_t)(row + j) * N + c] = acc[m][n][j];
      }
    }
  } else {
    const int b = bm >> 10;
    const int s0 = bm & 1023;
    const int hd2 = by * 2 + wc;  // 0..31
    if (hd2 < 24) {
      const bool isQ = (hd2 < 16);
      const float* nw = isQ ? qnw : knw;
      _Float16* dst = isQ ? qh : kh;
      const int ncols = isQ ? (NH * HD) : (NKV * HD);
      const int hcol = (isQ ? hd2 : (hd2 - 16)) * HD;
      float nwv[4];
#pragma unroll
      for (int n = 0; n < 4; ++n) nwv[n] = nw[n * 16 + lr];
#pragma unroll
      for (int m = 0; m < 4; ++m) {
#pragma unroll
        for (int j = 0; j < 4; ++j) {
          const int row = bm + wr * 64 + m * 16 + lk * 4 + j;
          float ss = 0.f;
#pragma unroll
          for (int n = 0; n < 4; ++n) ss += acc[m][n][j] * acc[m][n][j];
#pragma unroll
          for (int o = 1; o < 16; o <<= 1) ss += __shfl_xor(ss, o);
          const float rs = rsqrtf(ss * (1.0f / 64.0f) + 1e-6f);
          float y[4];
#pragma unroll
          for (int n = 0; n < 4; ++n) y[n] = acc[m][n][j] * rs * nwv[n];
          const size_t rb = (size_t)row * HD;
#pragma unroll
          for (int n = 0; n < 4; ++n) {
            const int d = n * 16 + lr;
            const float rot = (n < 2) ? -y[n + 2] : y[n - 2];
            dst[(size_t)row * ncols + hcol + d] =
                (_Float16)(y[n] * cosd[rb + d] + rot * sind[rb + d]);
          }
        }
      }
    } else {
      const int kv = hd2 - 24;
#pragma unroll
      for (int m = 0; m < 4; ++m) {
        const int sbase = s0 + wr * 64 + m * 16 + lk * 4;
#pragma unroll
        for (int n = 0; n < 4; ++n) {
          const int d = n * 16 + lr;
          f16x4 pk;
#pragma unroll
          for (int j = 0; j < 4; ++j) pk[j] = (_Float16)acc[m][n][j];
          *(f16x4*)&vTp[((size_t)((b * NKV + kv) * HD + d)) * Ss + sbase] = pk;
        }
      }
    }
  }
}

// ------------- O-projection GEMM, BM=128 BN=64 BK=32 (grid 512 = 2/CU) -----
__global__ __launch_bounds__(256) void gemm_oproj(
    const _Float16* __restrict__ A, const _Float16* __restrict__ Bt,
    float* __restrict__ C, int N, int K) {
  __shared__ __align__(16) _Float16 As[128][32];
  __shared__ __align__(16) _Float16 Bs[64][32];
  const int tid = threadIdx.x;
  const int wave = tid >> 6, lane = tid & 63;
  const int lr = lane & 15, lk = lane >> 4;
  const int bm = blockIdx.x * 128;
  const int bn = blockIdx.y * 64;

  f32x4 acc[2][4] = {};

  const int ca0 = wave * 128 + lane;
  const int cb0 = wave * 64 + lane;
  const _Float16* Arow0 = A + (size_t)(bm + (ca0 >> 2)) * K + (ca0 & 3) * 8;
  const _Float16* Arow1 = A + (size_t)(bm + ((ca0 + 64) >> 2)) * K + ((ca0 + 64) & 3) * 8;
  const _Float16* Brow  = Bt + (size_t)(bn + (cb0 >> 2)) * K + (cb0 & 3) * 8;
  _Float16* lA0 = &As[0][0] + ca0 * 8;
  _Float16* lA1 = &As[0][0] + (ca0 + 64) * 8;
  _Float16* lB  = &Bs[0][0] + cb0 * 8;

  for (int k0 = 0; k0 < K; k0 += 32) {
    __syncthreads();
    gl_lds16(Arow0 + k0, lA0);
    gl_lds16(Arow1 + k0, lA1);
    gl_lds16(Brow + k0, lB);
    __syncthreads();
    f16x8 af[2], bf[4];
#pragma unroll
    for (int m = 0; m < 2; ++m)
      af[m] = *(const f16x8*)&As[wave * 32 + m * 16 + lr][lk * 8];
#pragma unroll
    for (int n = 0; n < 4; ++n)
      bf[n] = *(const f16x8*)&Bs[n * 16 + lr][lk * 8];
#pragma unroll
    for (int m = 0; m < 2; ++m)
#pragma unroll
      for (int n = 0; n < 4; ++n)
        acc[m][n] =
            __builtin_amdgcn_mfma_f32_16x16x32_f16(af[m], bf[n], acc[m][n], 0, 0, 0);
  }
#pragma unroll
  for (int m = 0; m < 2; ++m) {
    const int row = bm + wave * 32 + m * 16 + lk * 4;
#pragma unroll
    for (int n = 0; n < 4; ++n) {
      const int c = bn + n * 16 + lr;
#pragma unroll
      for (int j = 0; j < 4; ++j)
        C[(size_t)(row + j) * N + c] = acc[m][n][j];
    }
  }
}

// ------------- MFMA flash attention, fixed softmax max (m = 8) --------------
// EXACT R6 structure (best-known: single-buffer K/V, 2-row staging, exp2f,
// diag-only masking, zero-tiles at end). ONE change: qt is remapped per batch
// so the 4 co-resident blocks on a CU (same blockIdx.x, different b) carry
// complementary qt -> per-CU tile-round load is uniform (34 per residue class
// instead of 8..128). Pure index permutation: coverage of (qt,h,b) unchanged,
// correctness independent of the hardware block->CU mapping.
__global__ __launch_bounds__(256) void attn_kernel(
    const _Float16* __restrict__ qh, const _Float16* __restrict__ kh,
    const _Float16* __restrict__ vT, float* __restrict__ attn,
    _Float16* __restrict__ ctxh) {
  __shared__ __align__(16) _Float16 Ks[64][72];
  __shared__ __align__(16) _Float16 Vs[64][72];
  __shared__ __align__(16) _Float16 Wh[4][16][72];
  const int x = blockIdx.x, h = blockIdx.y, b = blockIdx.z;
  int qt;
  switch (b) {
    case 0:  qt = x; break;
    case 1:  qt = 15 - x; break;
    case 2:  qt = (x + 8) & 15; break;
    default: qt = (7 - x) & 15; break;
  }
  const int kvh = h >> 1;  // GQA groups = 2
  const int tid = threadIdx.x, wave = tid >> 6, lane = tid & 63;
  const int lr = lane & 15, lk = lane >> 4;
  const int q0 = qt * 64, qrow0 = q0 + wave * 16;
  float* attn_bh = attn + (size_t)(b * NH + h) * Ss * Ss;

  // staging: thread covers rows sr, sr+32 at 16B chunk sc
  const int sr = tid >> 3, sc = tid & 7;
  const _Float16* kb0 = kh + (size_t)(b * Ss) * (NKV * HD) + kvh * HD + sc * 8;
  const _Float16* vb0 = vT + (size_t)((b * NKV + kvh) * HD) * Ss + sc * 8;

  // Q A-fragments direct from global (once per block)
  const _Float16* qp = qh + (size_t)(b * Ss + qrow0 + lr) * (NH * HD) + h * HD + lk * 8;
  const f16x8 aq0 = *(const f16x8*)qp;
  const f16x8 aq1 = *(const f16x8*)(qp + 32);

  const float C1 = 0.18033688011112042f;  // 0.125 * log2(e)
  const float C2 = -11.541560327111707f;  // -8 * log2(e)

  // ---- pass A: softmax denominators only ----
  f16x8 pk0 = *(const f16x8*)(kb0 + (size_t)sr * (NKV * HD));
  f16x8 pk1 = *(const f16x8*)(kb0 + (size_t)(sr + 32) * (NKV * HD));
  float lsum[4] = {0.f, 0.f, 0.f, 0.f};
  for (int t = 0; t <= qt; ++t) {
    __syncthreads();  // previous tile's LDS reads done
    *(f16x8*)&Ks[sr][sc * 8] = pk0;
    *(f16x8*)&Ks[sr + 32][sc * 8] = pk1;
    if (t < qt) {
      pk0 = *(const f16x8*)(kb0 + (size_t)((t + 1) * 64 + sr) * (NKV * HD));
      pk1 = *(const f16x8*)(kb0 + (size_t)((t + 1) * 64 + sr + 32) * (NKV * HD));
    }
    __syncthreads();
    f32x4 acc[4] = {};
#pragma unroll
    for (int n = 0; n < 4; ++n) {
      f16x8 b0 = *(const f16x8*)&Ks[n * 16 + lr][lk * 8];
      acc[n] = __builtin_amdgcn_mfma_f32_16x16x32_f16(aq0, b0, acc[n], 0, 0, 0);
    }
#pragma unroll
    for (int n = 0; n < 4; ++n) {
      f16x8 b1 = *(const f16x8*)&Ks[n * 16 + lr][32 + lk * 8];
      acc[n] = __builtin_amdgcn_mfma_f32_16x16x32_f16(aq1, b1, acc[n], 0, 0, 0);
    }
    if (t < qt) {  // full tile: no mask
#pragma unroll
      for (int j = 0; j < 4; ++j)
#pragma unroll
        for (int n = 0; n < 4; ++n) lsum[j] += exp2f(fmaf(acc[n][j], C1, C2));
    } else {  // diagonal tile: the only masked one
#pragma unroll
      for (int j = 0; j < 4; ++j) {
        const int gr = qrow0 + lk * 4 + j;
#pragma unroll
        for (int n = 0; n < 4; ++n) {
          float p = exp2f(fmaf(acc[n][j], C1, C2));
          if (q0 + n * 16 + lr > gr) p = 0.f;
          lsum[j] += p;
        }
      }
    }
  }
  float linv[4];
#pragma unroll
  for (int j = 0; j < 4; ++j) {
#pragma unroll
    for (int o = 1; o < 16; o <<= 1) lsum[j] += __shfl_xor(lsum[j], o);
    linv[j] = 1.0f / lsum[j];
  }

  // ---- pass B: recompute scores, write weights once, PV accumulate ----
  pk0 = *(const f16x8*)(kb0 + (size_t)sr * (NKV * HD));
  pk1 = *(const f16x8*)(kb0 + (size_t)(sr + 32) * (NKV * HD));
  f16x8 pv0 = *(const f16x8*)(vb0 + (size_t)sr * Ss);
  f16x8 pv1 = *(const f16x8*)(vb0 + (size_t)(sr + 32) * Ss);
  f32x4 acc2[4] = {};
  for (int t = 0; t <= qt; ++t) {
    __syncthreads();
    *(f16x8*)&Ks[sr][sc * 8] = pk0;
    *(f16x8*)&Ks[sr + 32][sc * 8] = pk1;
    *(f16x8*)&Vs[sr][sc * 8] = pv0;
    *(f16x8*)&Vs[sr + 32][sc * 8] = pv1;
    if (t < qt) {
      pk0 = *(const f16x8*)(kb0 + (size_t)((t + 1) * 64 + sr) * (NKV * HD));
      pk1 = *(const f16x8*)(kb0 + (size_t)((t + 1) * 64 + sr + 32) * (NKV * HD));
      pv0 = *(const f16x8*)(vb0 + (size_t)sr * Ss + (t + 1) * 64);
      pv1 = *(const f16x8*)(vb0 + (size_t)(sr + 32) * Ss + (t + 1) * 64);
    }
    __syncthreads();
    f32x4 acc[4] = {};
#pragma unroll
    for (int n = 0; n < 4; ++n) {
      f16x8 b0 = *(const f16x8*)&Ks[n * 16 + lr][lk * 8];
      acc[n] = __builtin_amdgcn_mfma_f32_16x16x32_f16(aq0, b0, acc[n], 0, 0, 0);
    }
#pragma unroll
    for (int n = 0; n < 4; ++n) {
      f16x8 b1 = *(const f16x8*)&Ks[n * 16 + lr][32 + lk * 8];
      acc[n] = __builtin_amdgcn_mfma_f32_16x16x32_f16(aq1, b1, acc[n], 0, 0, 0);
    }
    if (t < qt) {
#pragma unroll
      for (int j = 0; j < 4; ++j)
#pragma unroll
        for (int n = 0; n < 4; ++n) {
          const float w = exp2f(fmaf(acc[n][j], C1, C2)) * linv[j];
          Wh[wave][lk * 4 + j][n * 16 + lr] = (_Float16)w;
        }
    } else {
#pragma unroll
      for (int j = 0; j < 4; ++j) {
        const int gr = qrow0 + lk * 4 + j;
#pragma unroll
        for (int n = 0; n < 4; ++n) {
          float w = exp2f(fmaf(acc[n][j], C1, C2)) * linv[j];
          if (q0 + n * 16 + lr > gr) w = 0.f;
          Wh[wave][lk * 4 + j][n * 16 + lr] = (_Float16)w;
        }
      }
    }
    // PV: A = Wh rows (own 16 q-rows), B = V^T tile (in-wave DS ordering)
#pragma unroll
    for (int kc = 0; kc < 2; ++kc) {
      f16x8 aw = *(const f16x8*)&Wh[wave][lr][kc * 32 + lk * 8];
#pragma unroll
      for (int n = 0; n < 4; ++n) {
        f16x8 bv = *(const f16x8*)&Vs[n * 16 + lr][kc * 32 + lk * 8];
        acc2[n] = __builtin_amdgcn_mfma_f32_16x16x32_f16(aw, bv, acc2[n], 0, 0, 0);
      }
    }
    // weights -> HBM via Wh (coalesced float4, cached stores)
    const int wr = lane >> 2;
    const int wc0 = (lane & 3) * 16;
#pragma unroll
    for (int i2 = 0; i2 < 4; ++i2) {
      f16x4 hv = *(const f16x4*)&Wh[wave][wr][wc0 + i2 * 4];
      *(float4*)&attn_bh[(size_t)(qrow0 + wr) * Ss + t * 64 + wc0 + i2 * 4] =
          make_float4((float)hv[0], (float)hv[1], (float)hv[2], (float)hv[3]);
    }
  }

  // zero the fully-masked tiles
  for (int t = qt + 1; t < 16; ++t)
    for (int idx = tid; idx < 1024; idx += 256) {
      int r = idx >> 4, c4 = (idx & 15) * 4;
      *(float4*)&attn_bh[(size_t)(q0 + r) * Ss + t * 64 + c4] =
          make_float4(0.f, 0.f, 0.f, 0.f);
    }

  // ctx store (fp16)
#pragma unroll
  for (int n = 0; n < 4; ++n)
#pragma unroll
    for (int j = 0; j < 4; ++j)
      ctxh[(size_t)(b * Ss + qrow0 + lk * 4 + j) * (NH * HD) + h * HD + n * 16 + lr] =
          (_Float16)acc2[n][j];
}

// ---------------- launch ----------------
extern "C" void kernel_launch(void* const* d_in, const int* in_sizes, int n_in,
                              void* d_out, int out_size, void* d_ws, size_t ws_size,
                              hipStream_t stream) {
  const float* hs   = (const float*)d_in[0];
  const float* cosb = (const float*)d_in[1];
  const float* sinb = (const float*)d_in[2];
  // d_in[3] attention_mask: causal, reproduced analytically
  const float* Wq = (const float*)d_in[4];
  const float* Wk = (const float*)d_in[5];
  const float* Wv = (const float*)d_in[6];
  const float* Wo = (const float*)d_in[7];
  const float* qw = (const float*)d_in[8];
  const float* kw = (const float*)d_in[9];

  char* ws = (char*)d_ws;
  _Float16* Xh    = (_Float16*)(ws);             // 4096x1024 fp16 (8 MB)
  _Float16* Wqkvh = (_Float16*)(ws + 8388608);   // 2048x1024 fp16 (4 MB) Q|K|V
  _Float16* Woh   = (_Float16*)(ws + 12582912);  // 1024x1024 fp16 (2 MB)
  _Float16* qh    = (_Float16*)(ws + 14680064);  // 4096x1024 fp16 (8 MB)
  _Float16* kh    = (_Float16*)(ws + 23068672);  // 4096x512  fp16 (4 MB)
  _Float16* vT    = (_Float16*)(ws + 27262976);  // [4*8*64][1024] (4 MB)
  _Float16* ctxh  = (_Float16*)(ws + 31457280);  // 4096x1024 fp16 (8 MB)

  float* out  = (float*)d_out;
  float* attn = out + (size_t)Bb * Ss * HID;

  f2h_all<<<7168, 256, 0, stream>>>(hs, Wq, Wk, Wv, Wo, Xh, Wqkvh,
                                    Wqkvh + 1048576, Wqkvh + 1572864, Woh);

  // fused QKV projection + RMSNorm/RoPE/V-transpose epilogues (128x128 tiles)
  gemm128<1><<<dim3(32, 16), 256, 0, stream>>>(
      Xh, Wqkvh, nullptr, qh, kh, vT, qw, kw, cosb, sinb, 2048, 1024);

  // attention: qt remapped per-batch for uniform per-CU load
  attn_kernel<<<dim3(16, 16, 4), 256, 0, stream>>>(qh, kh, vT, attn, ctxh);

  // O-projection
  gemm_oproj<<<dim3(32, 16), 256, 0, stream>>>(ctxh, Woh, out, 1024, 1024);
}